// Round 2
// baseline (1526.416 us; speedup 1.0000x reference)
//
#include <hip/hip_runtime.h>
#include <hip/hip_bf16.h>

namespace {

constexpr int T_   = 8;
constexpr int NTOK = 8192;    // B*S
constexpr int LAT  = 1024;
constexpr int SYM  = 256;
constexpr int NC   = 512;

// ---------------- routing: one wave per token -------------------------------
__global__ void route_k(const float* __restrict__ syms, const float* __restrict__ Wq,
                        int* __restrict__ top, int* __restrict__ counts){
  int gt = blockIdx.x * blockDim.x + threadIdx.x;
  int wid = gt >> 6, lane = gt & 63;
  if (wid >= NTOK) return;
  float4 wq = *(const float4*)(Wq + lane * 4);
  float best = -INFINITY; int bt = 0;
  for (int t = 0; t < T_; ++t){
    float4 s = *(const float4*)(syms + ((size_t)t * NTOK + wid) * SYM + lane * 4);
    float p = s.x*wq.x + s.y*wq.y + s.z*wq.z + s.w*wq.w;
    #pragma unroll
    for (int off = 32; off; off >>= 1) p += __shfl_down(p, off, 64);
    p = __shfl(p, 0, 64);               // bq is a constant shift: argmax unchanged
    if (p > best){ best = p; bt = t; }  // strict > == first-occurrence argmax
  }
  if (lane == 0){ top[wid] = bt; atomicAdd(&counts[bt], 1); }
}

__global__ void mask_k(const int* __restrict__ counts, float* __restrict__ out_mask){
  int t = threadIdx.x;
  if (t < T_) out_mask[t] = (counts[t] == 0) ? 1.0f : 0.0f;
}

// codebook transpose: cbT[k*NC + c] = cb[c*SYM + k]
__global__ void cbt_k(const float* __restrict__ cb, float* __restrict__ cbT){
  int i = blockIdx.x * blockDim.x + threadIdx.x;
  if (i < NC * SYM){ int c = i / SYM, k = i % SYM; cbT[k * NC + c] = cb[i]; }
}

// per-code squared norms: one wave per code
__global__ void cnorm_k(const float* __restrict__ cb, float* __restrict__ cnorm){
  int gt = blockIdx.x * blockDim.x + threadIdx.x;
  int wid = gt >> 6, lane = gt & 63;
  if (wid >= NC) return;
  float4 v = *(const float4*)(cb + (size_t)wid * SYM + lane * 4);
  float p = v.x*v.x + v.y*v.y + v.z*v.z + v.w*v.w;
  #pragma unroll
  for (int off = 32; off; off >>= 1) p += __shfl_down(p, off, 64);
  if (lane == 0) cnorm[wid] = p;
}

// ---------------- VQ argmin + quantized gather: one wave per token ----------
// writes f32 quantized rows directly into d_out chunk 1, f32 indices chunk 2
__global__ void vq_k(const float* __restrict__ d2h, const float* __restrict__ cb,
                     float* __restrict__ out_q, float* __restrict__ out_idx){
  int gt = blockIdx.x * blockDim.x + threadIdx.x;
  int wid = gt >> 6, lane = gt & 63;
  if (wid >= NTOK) return;
  const float* row = d2h + (size_t)wid * NC;
  float mv = INFINITY; int mi = 0x7fffffff;
  #pragma unroll
  for (int i = 0; i < NC / 64; ++i){
    int idx = i * 64 + lane;
    float v = row[idx];
    if (v < mv){ mv = v; mi = idx; }    // per-lane ascending: strict < keeps first
  }
  #pragma unroll
  for (int off = 32; off; off >>= 1){
    float ov = __shfl_down(mv, off, 64);
    int   oi = __shfl_down(mi, off, 64);
    if (ov < mv || (ov == mv && oi < mi)){ mv = ov; mi = oi; }
  }
  mi = __shfl(mi, 0, 64);
  if (lane == 0) out_idx[wid] = (float)mi;
  float4 c = *(const float4*)(cb + (size_t)mi * SYM + lane * 4);
  *(float4*)(out_q + (size_t)wid * SYM + lane * 4) = c;
}

// ---------------- templated f32 tiled GEMM ----------------------------------
constexpr int A_PLAIN = 0, A_BUS = 1, A_CAT = 2;
constexpr int E_BIAS = 0, E_VQ = 1, E_RELU = 2, E_RESID = 3;

template<int BM, int BN, int BK, int TM, int TN, int ASRC, int EPI>
__global__ __launch_bounds__((BM/TM)*(BN/TN))
void gemm_k(const float* __restrict__ A, const float* __restrict__ A2,
            const int* __restrict__ topidx,
            const float* __restrict__ Bm, const float* __restrict__ bias,
            float* __restrict__ Cf, const float* __restrict__ resid,
            int M, int N, int K, int asplit)
{
  constexpr int NT  = (BM/TM)*(BN/TN);
  constexpr int BMp = BM + 4, BNp = BN + 4;
  constexpr int KV  = BK / 4;          // float4 chunks along k per A-row
  constexpr int NLA = BM * KV;         // total float4 loads for A tile
  constexpr int NLB = (BK * BN) / 4;   // total float4 loads for B tile
  __shared__ float As[BK][BMp];
  __shared__ float Bs[BK][BNp];

  const int tid = threadIdx.x;
  const int tx = tid % (BN / TN), ty = tid / (BN / TN);
  const int m0 = blockIdx.x * BM, n0 = blockIdx.y * BN;

  float acc[TM][TN];
  #pragma unroll
  for (int i = 0; i < TM; ++i)
    #pragma unroll
    for (int j = 0; j < TN; ++j) acc[i][j] = 0.f;

  for (int k0 = 0; k0 < K; k0 += BK){
    #pragma unroll
    for (int q = tid; q < NLA; q += NT){
      int m = q / KV, kq = (q % KV) * 4;
      int gm = m0 + m, gk = k0 + kq;
      float4 v;
      if constexpr (ASRC == A_PLAIN){
        v = *(const float4*)(A + (size_t)gm * K + gk);
      } else if constexpr (ASRC == A_BUS){
        if (gk < asplit) v = *(const float4*)(A + (size_t)gm * asplit + gk);
        else {
          int t = topidx[gm];
          v = *(const float4*)(A2 + ((size_t)t * NTOK + gm) * LAT + (gk - asplit));
        }
      } else { // A_CAT
        if (gk < asplit) v = *(const float4*)(A + (size_t)gm * asplit + gk);
        else             v = *(const float4*)(A2 + (size_t)gm * (K - asplit) + (gk - asplit));
      }
      As[kq+0][m] = v.x; As[kq+1][m] = v.y; As[kq+2][m] = v.z; As[kq+3][m] = v.w;
    }
    #pragma unroll
    for (int q = tid; q < NLB; q += NT){
      int k = q / (BN / 4), n4 = (q % (BN / 4)) * 4;
      *(float4*)&Bs[k][n4] = *(const float4*)(Bm + (size_t)(k0 + k) * N + n0 + n4);
    }
    __syncthreads();
    #pragma unroll
    for (int k = 0; k < BK; ++k){
      float a[TM], b[TN];
      #pragma unroll
      for (int i = 0; i < TM; ++i) a[i] = As[k][ty*TM + i];
      #pragma unroll
      for (int j = 0; j < TN; ++j) b[j] = Bs[k][tx*TN + j];
      #pragma unroll
      for (int i = 0; i < TM; ++i)
        #pragma unroll
        for (int j = 0; j < TN; ++j) acc[i][j] += a[i] * b[j];
    }
    __syncthreads();
  }

  #pragma unroll
  for (int i = 0; i < TM; ++i){
    int gm = m0 + ty*TM + i;
    #pragma unroll
    for (int j = 0; j < TN; ++j){
      int gn = n0 + tx*TN + j;
      float v = acc[i][j];
      if constexpr (EPI == E_BIAS){
        Cf[(size_t)gm * N + gn] = v + bias[gn];
      } else if constexpr (EPI == E_VQ){
        Cf[(size_t)gm * N + gn] = bias[gn] - 2.f * v;   // bias = ||c||^2
      } else if constexpr (EPI == E_RELU){
        v += bias[gn];
        Cf[(size_t)gm * N + gn] = v > 0.f ? v : 0.f;
      } else { // E_RESID
        Cf[(size_t)gm * N + gn] = v + bias[gn] + resid[(size_t)gm * N + gn];
      }
    }
  }
}

} // namespace

extern "C" void kernel_launch(void* const* d_in, const int* in_sizes, int n_in,
                              void* d_out, int out_size, void* d_ws, size_t ws_size,
                              hipStream_t stream){
  const float* token_state = (const float*)d_in[0];
  const float* bus_symbols = (const float*)d_in[1];
  const float* bus_outputs = (const float*)d_in[3];
  const float* Wq    = (const float*)d_in[5];
  const float* Wread = (const float*)d_in[7];
  const float* bread = (const float*)d_in[8];
  const float* Wsym  = (const float*)d_in[9];
  const float* bsym  = (const float*)d_in[10];
  const float* Wc1   = (const float*)d_in[11];
  const float* bc1   = (const float*)d_in[12];
  const float* Wc2   = (const float*)d_in[13];
  const float* bc2   = (const float*)d_in[14];
  const float* codebook = (const float*)d_in[15];

  // d_out is FLOAT32 (reference output dtype), outputs concatenated flat:
  float* out_node = (float*)d_out;                                   // [NTOK*LAT]
  float* out_quant= out_node + (size_t)NTOK * LAT;                   // [NTOK*SYM]
  float* out_idx  = out_quant + (size_t)NTOK * SYM;                  // [NTOK]
  float* out_mask = out_idx + NTOK;                                  // [T]

  int* top    = (int*)d_ws;            // [8192]
  int* counts = top + NTOK;            // [8]
  float* wsf  = (float*)d_ws;
  float* cbT    = wsf + 8448;                      // [SYM*NC]   (k-major)
  float* cnorm  = cbT + (size_t)SYM * NC;          // [NC]
  float* zread  = cnorm + 512;                     // [NTOK*LAT]
  float* raw    = zread + (size_t)NTOK * LAT;      // [NTOK*SYM]
  float* d2h    = raw + (size_t)NTOK * SYM;        // [NTOK*NC]
  float* hbuf   = d2h + (size_t)NTOK * NC;         // [NTOK*LAT]

  hipMemsetAsync(counts, 0, T_ * sizeof(int), stream);
  route_k<<<NTOK/4, 256, 0, stream>>>(bus_symbols, Wq, top, counts);
  mask_k<<<1, 64, 0, stream>>>(counts, out_mask);
  cbt_k<<<(NC*SYM)/256, 256, 0, stream>>>(codebook, cbT);
  cnorm_k<<<NC/4, 256, 0, stream>>>(codebook, cnorm);

  // z_read = [token_state | chosen(bus_outputs, top)] @ Wread + bread
  gemm_k<128,128,8,8,8,A_BUS,E_BIAS><<<dim3(64,8), 256, 0, stream>>>(
      token_state, bus_outputs, top, Wread, bread, zread, nullptr,
      NTOK, LAT, 2*LAT, LAT);
  // raw_symbol = z_read @ Wsym + bsym
  gemm_k<64,64,8,4,4,A_PLAIN,E_BIAS><<<dim3(128,4), 256, 0, stream>>>(
      zread, nullptr, nullptr, Wsym, bsym, raw, nullptr,
      NTOK, SYM, LAT, 0);
  // d2h = ||c||^2 - 2 * raw @ cbT   (argmin-equivalent distances)
  gemm_k<64,128,8,4,8,A_PLAIN,E_VQ><<<dim3(128,4), 256, 0, stream>>>(
      raw, nullptr, nullptr, cbT, cnorm, d2h, nullptr,
      NTOK, NC, SYM, 0);
  // VQ argmin -> f32 indices + f32 quantized rows (directly into d_out)
  vq_k<<<NTOK/4, 256, 0, stream>>>(d2h, codebook, out_quant, out_idx);
  // h = relu([z_read | quantized] @ Wc1 + bc1)
  gemm_k<128,128,8,8,8,A_CAT,E_RELU><<<dim3(64,8), 256, 0, stream>>>(
      zread, out_quant, nullptr, Wc1, bc1, hbuf, nullptr,
      NTOK, LAT, LAT+SYM, LAT);
  // node_output = h @ Wc2 + bc2 + token_state  (f32 out)
  gemm_k<128,128,8,8,8,A_PLAIN,E_RESID><<<dim3(64,8), 256, 0, stream>>>(
      hbuf, nullptr, nullptr, Wc2, bc2, out_node, token_state,
      NTOK, LAT, LAT, 0);
}

// Round 3
// 1012.840 us; speedup vs baseline: 1.5071x; 1.5071x over previous
//
#include <hip/hip_runtime.h>
#include <hip/hip_bf16.h>

#define DEVI __device__ __forceinline__

namespace {

constexpr int T_   = 8;
constexpr int NTOK = 8192;    // B*S
constexpr int LAT  = 1024;
constexpr int SYM  = 256;
constexpr int NC   = 512;
constexpr float TAU = 0.6f;   // repair margin (approx-score error sigma ~0.07)

typedef short short8 __attribute__((ext_vector_type(8)));
typedef float floatx4 __attribute__((ext_vector_type(4)));

DEVI unsigned short f2bf(float f){
  union { float f; unsigned u; } v; v.f = f;
  return (unsigned short)((v.u + 0x7fffu + ((v.u >> 16) & 1u)) >> 16);
}

// ---------------- routing: one wave per token -------------------------------
__global__ void route_k(const float* __restrict__ syms, const float* __restrict__ Wq,
                        int* __restrict__ top, int* __restrict__ counts){
  int gt = blockIdx.x * blockDim.x + threadIdx.x;
  int wid = gt >> 6, lane = gt & 63;
  if (wid >= NTOK) return;
  float4 wq = *(const float4*)(Wq + lane * 4);
  float best = -INFINITY; int bt = 0;
  for (int t = 0; t < T_; ++t){
    float4 s = *(const float4*)(syms + ((size_t)t * NTOK + wid) * SYM + lane * 4);
    float p = s.x*wq.x + s.y*wq.y + s.z*wq.z + s.w*wq.w;
    #pragma unroll
    for (int off = 32; off; off >>= 1) p += __shfl_down(p, off, 64);
    p = __shfl(p, 0, 64);
    if (p > best){ best = p; bt = t; }
  }
  if (lane == 0){ top[wid] = bt; atomicAdd(&counts[bt], 1); }
}

__global__ void mask_k(const int* __restrict__ counts, float* __restrict__ out_mask){
  int t = threadIdx.x;
  if (t < T_) out_mask[t] = (counts[t] == 0) ? 1.0f : 0.0f;
}

// codebook transpose: cbT[k*NC + c] = cb[c*SYM + k]  (f32)
__global__ void cbt_k(const float* __restrict__ cb, float* __restrict__ cbT){
  int i = blockIdx.x * blockDim.x + threadIdx.x;
  if (i < NC * SYM){ int c = i / SYM, k = i % SYM; cbT[k * NC + c] = cb[i]; }
}

// cnorm[c] = ||cb_c||^2 ; svec[c] = sum_k cb[c][k]*(cb[c][k]-2*bsym[k])
__global__ void cnorm_k(const float* __restrict__ cb, const float* __restrict__ bsym,
                        float* __restrict__ cnorm, float* __restrict__ svec){
  int gt = blockIdx.x * blockDim.x + threadIdx.x;
  int wid = gt >> 6, lane = gt & 63;
  if (wid >= NC) return;
  float4 v = *(const float4*)(cb + (size_t)wid * SYM + lane * 4);
  float4 b = *(const float4*)(bsym + lane * 4);
  float p = v.x*v.x + v.y*v.y + v.z*v.z + v.w*v.w;
  float q = v.x*(v.x-2.f*b.x) + v.y*(v.y-2.f*b.y) + v.z*(v.z-2.f*b.z) + v.w*(v.w-2.f*b.w);
  #pragma unroll
  for (int off = 32; off; off >>= 1){ p += __shfl_down(p, off, 64); q += __shfl_down(q, off, 64); }
  if (lane == 0){ cnorm[wid] = p; svec[wid] = q; }
}

// raw_bias[j] = bsym[j] + sum_k bread[k]*Wsym[k*SYM + j]
__global__ void rbias_k(const float* __restrict__ bread, const float* __restrict__ Wsym,
                        const float* __restrict__ bsym, float* __restrict__ rb){
  int t = threadIdx.x;
  float acc = bsym[t];
  for (int k = 0; k < LAT; ++k) acc += bread[k] * Wsym[(size_t)k * SYM + t];
  rb[t] = acc;
}

// tiled transpose f32[R x C] -> bf16[C x R]
__global__ void t32_k(const float* __restrict__ in, unsigned short* __restrict__ out,
                      int R, int C){
  __shared__ float tile[32][33];
  int tid = threadIdx.x;
  int tx = tid & 31, ty = tid >> 5;            // ty 0..7
  int r0 = blockIdx.y * 32, c0 = blockIdx.x * 32;
  #pragma unroll
  for (int j = 0; j < 4; ++j)
    tile[ty + j*8][tx] = in[(size_t)(r0 + ty + j*8) * C + c0 + tx];
  __syncthreads();
  #pragma unroll
  for (int j = 0; j < 4; ++j)
    out[(size_t)(c0 + ty + j*8) * R + r0 + tx] = f2bf(tile[tx][ty + j*8]);
}

// pack A_z bf16 [NTOK x 2*LAT] = [bf16(token_state) | bf16(bus_outputs[top])]
__global__ void pack_az(const float* __restrict__ ts, const float* __restrict__ bus,
                        const int* __restrict__ top, unsigned short* __restrict__ Az){
  int id = blockIdx.x * blockDim.x + threadIdx.x;
  int m = id >> 9, c = (id & 511) * 4;
  const float* src = (c < LAT) ? (ts + (size_t)m * LAT + c)
                               : (bus + ((size_t)top[m] * NTOK + m) * LAT + (c - LAT));
  float4 v = *(const float4*)src;
  ushort4 o; o.x = f2bf(v.x); o.y = f2bf(v.y); o.z = f2bf(v.z); o.w = f2bf(v.w);
  *(ushort4*)(Az + (size_t)m * (2*LAT) + c) = o;
}

// ---------------- f32 tiled GEMM (small prep matmuls only) ------------------
constexpr int E_NONE = 0;
template<int BM, int BN, int BK, int TM, int TN>
__global__ __launch_bounds__((BM/TM)*(BN/TN))
void gemm_f32(const float* __restrict__ A, const float* __restrict__ Bm,
              float* __restrict__ Cf, int M, int N, int K)
{
  constexpr int NT  = (BM/TM)*(BN/TN);
  constexpr int BMp = BM + 4, BNp = BN + 4;
  constexpr int KV  = BK / 4;
  constexpr int NLA = BM * KV;
  constexpr int NLB = (BK * BN) / 4;
  __shared__ float As[BK][BMp];
  __shared__ float Bs[BK][BNp];
  const int tid = threadIdx.x;
  const int tx = tid % (BN / TN), ty = tid / (BN / TN);
  const int m0 = blockIdx.x * BM, n0 = blockIdx.y * BN;
  float acc[TM][TN] = {};
  for (int k0 = 0; k0 < K; k0 += BK){
    for (int q = tid; q < NLA; q += NT){
      int m = q / KV, kq = (q % KV) * 4;
      float4 v = *(const float4*)(A + (size_t)(m0+m) * K + k0 + kq);
      As[kq+0][m] = v.x; As[kq+1][m] = v.y; As[kq+2][m] = v.z; As[kq+3][m] = v.w;
    }
    for (int q = tid; q < NLB; q += NT){
      int k = q / (BN/4), n4 = (q % (BN/4)) * 4;
      *(float4*)&Bs[k][n4] = *(const float4*)(Bm + (size_t)(k0+k) * N + n0 + n4);
    }
    __syncthreads();
    #pragma unroll
    for (int k = 0; k < BK; ++k){
      float a[TM], b[TN];
      #pragma unroll
      for (int i = 0; i < TM; ++i) a[i] = As[k][ty*TM + i];
      #pragma unroll
      for (int j = 0; j < TN; ++j) b[j] = Bs[k][tx*TN + j];
      #pragma unroll
      for (int i = 0; i < TM; ++i)
        #pragma unroll
        for (int j = 0; j < TN; ++j) acc[i][j] += a[i] * b[j];
    }
    __syncthreads();
  }
  #pragma unroll
  for (int i = 0; i < TM; ++i)
    #pragma unroll
    for (int j = 0; j < TN; ++j)
      Cf[(size_t)(m0 + ty*TM + i) * N + n0 + tx*TN + j] = acc[i][j];
}

// ---------------- MFMA bf16 GEMM: C = A @ BT^T ------------------------------
// A [M x K] bf16 RM (CAT: A stride asplit, A2 stride K-asplit), BT [N x K] bf16 RM.
// 128x128 tile, BK=32, 4 waves (2x2), each wave 64x64 = 4x4 mfma_16x16x32.
constexpr int A_PLAIN = 0, A_CAT = 1;
constexpr int EP_ZH = 0, EP_VQ = 1, EP_RELU = 2, EP_OUT = 3;

template<int ASRC, int EPI>
__global__ __launch_bounds__(256)
void mgemm(const unsigned short* __restrict__ A, const unsigned short* __restrict__ A2,
           const unsigned short* __restrict__ BT, const float* __restrict__ bias,
           const float* __restrict__ resid,
           unsigned short* __restrict__ Cb, float* __restrict__ Cf,
           int N, int K, int asplit)
{
  __shared__ unsigned short As[128*32];
  __shared__ unsigned short Bs[128*32];
  const int tid  = threadIdx.x;
  const int wave = tid >> 6, lane = tid & 63;
  const int wy = wave >> 1, wx = wave & 1;
  const int lq = lane >> 4, lr = lane & 15;
  const int m0 = blockIdx.y * 128, n0 = blockIdx.x * 128;

  floatx4 acc[4][4] = {};

  for (int k0 = 0; k0 < K; k0 += 32){
    #pragma unroll
    for (int c = 0; c < 2; ++c){
      int chunk = tid + c*256;                 // 0..511
      int mrel = chunk >> 2, kc = (chunk & 3) * 8;
      int gk = k0 + kc;
      const unsigned short* srcA;
      if constexpr (ASRC == A_CAT){
        if (gk < asplit) srcA = A  + (size_t)(m0+mrel) * asplit + gk;
        else             srcA = A2 + (size_t)(m0+mrel) * (K-asplit) + (gk-asplit);
      } else {
        srcA = A + (size_t)(m0+mrel) * K + gk;
      }
      *(uint4*)&As[mrel*32 + kc] = *(const uint4*)srcA;
      *(uint4*)&Bs[mrel*32 + kc] = *(const uint4*)(BT + (size_t)(n0+mrel) * K + gk);
    }
    __syncthreads();
    short8 af[4], bf[4];
    #pragma unroll
    for (int i = 0; i < 4; ++i){
      af[i] = *(const short8*)&As[(wy*64 + i*16 + lr)*32 + lq*8];
      bf[i] = *(const short8*)&Bs[(wx*64 + i*16 + lr)*32 + lq*8];
    }
    #pragma unroll
    for (int i = 0; i < 4; ++i)
      #pragma unroll
      for (int j = 0; j < 4; ++j)
        acc[i][j] = __builtin_amdgcn_mfma_f32_16x16x32_bf16(af[i], bf[j], acc[i][j], 0, 0, 0);
    __syncthreads();
  }

  #pragma unroll
  for (int i = 0; i < 4; ++i){
    #pragma unroll
    for (int j = 0; j < 4; ++j){
      int gn = n0 + wx*64 + j*16 + lr;
      #pragma unroll
      for (int r = 0; r < 4; ++r){
        int gm = m0 + wy*64 + i*16 + lq*4 + r;
        float v = acc[i][j][r];
        if constexpr (EPI == EP_ZH){
          Cb[(size_t)gm * N + gn] = f2bf(v + bias[gn]);
        } else if constexpr (EPI == EP_VQ){
          Cf[(size_t)gm * N + gn] = bias[gn] - 2.f * v;     // bias = svec
        } else if constexpr (EPI == EP_RELU){
          float u = v + bias[gn];
          Cb[(size_t)gm * N + gn] = f2bf(u > 0.f ? u : 0.f);
        } else {
          Cf[(size_t)gm * N + gn] = v + bias[gn] + resid[(size_t)gm * N + gn];
        }
      }
    }
  }
}

// ---------------- VQ: top-2 margin argmin + gather + repair flagging --------
__global__ void vq_k(const float* __restrict__ scores, const float* __restrict__ cb,
                     float* __restrict__ out_q, float* __restrict__ out_idx,
                     unsigned short* __restrict__ q_h,
                     int* __restrict__ rcount, int* __restrict__ rlist){
  int gt = blockIdx.x * blockDim.x + threadIdx.x;
  int wid = gt >> 6, lane = gt & 63;
  if (wid >= NTOK) return;
  const float* row = scores + (size_t)wid * NC;
  float v1 = INFINITY, v2 = INFINITY; int i1 = 0x7fffffff;
  #pragma unroll
  for (int i = 0; i < NC/64; ++i){
    int c = i*64 + lane;
    float v = row[c];
    if (v < v1){ v2 = v1; v1 = v; i1 = c; } else v2 = fminf(v2, v);
  }
  #pragma unroll
  for (int off = 32; off; off >>= 1){
    float ov1 = __shfl_down(v1, off, 64);
    int   oi1 = __shfl_down(i1, off, 64);
    float ov2 = __shfl_down(v2, off, 64);
    float rest;
    if (ov1 < v1 || (ov1 == v1 && oi1 < i1)){ rest = v1; v1 = ov1; i1 = oi1; }
    else rest = ov1;
    v2 = fminf(fminf(v2, ov2), rest);
  }
  i1 = __shfl(i1, 0, 64);
  if (lane == 0){
    out_idx[wid] = (float)i1;
    if (__shfl(v2, 0, 64) - __shfl(v1, 0, 64) < TAU){
      int p = atomicAdd(rcount, 1); rlist[p] = wid;
    }
  }
  float4 cv = *(const float4*)(cb + (size_t)i1 * SYM + lane * 4);
  *(float4*)(out_q + (size_t)wid * SYM + lane * 4) = cv;
  ushort4 qh; qh.x = f2bf(cv.x); qh.y = f2bf(cv.y); qh.z = f2bf(cv.z); qh.w = f2bf(cv.w);
  *(ushort4*)(q_h + (size_t)wid * SYM + lane * 4) = qh;
}

// ---------------- exact f32 repair for near-tie tokens ----------------------
__global__ __launch_bounds__(256)
void repair_k(const int* __restrict__ rcount, const int* __restrict__ rlist,
              const int* __restrict__ top,
              const float* __restrict__ ts, const float* __restrict__ bus,
              const float* __restrict__ Wcomb, const float* __restrict__ rb,
              const float* __restrict__ cb, const float* __restrict__ cnorm,
              float* __restrict__ out_q, float* __restrict__ out_idx,
              unsigned short* __restrict__ q_h){
  __shared__ float a[2*LAT];
  __shared__ float raw[SYM];
  __shared__ float rv[256]; __shared__ int ri[256];
  int tid = threadIdx.x;
  int cnt = *rcount;
  for (int b = blockIdx.x; b < cnt; b += gridDim.x){
    int m = rlist[b]; int t = top[m];
    for (int i = tid; i < 512; i += 256){
      int c = i * 4;
      float4 v = (c < LAT) ? *(const float4*)(ts + (size_t)m * LAT + c)
                           : *(const float4*)(bus + ((size_t)t * NTOK + m) * LAT + (c - LAT));
      *(float4*)&a[c] = v;
    }
    __syncthreads();
    float acc = rb[tid];
    for (int k = 0; k < 2*LAT; ++k) acc += a[k] * Wcomb[(size_t)k * SYM + tid];
    raw[tid] = acc;
    __syncthreads();
    float bv = INFINITY; int bi = 0;
    #pragma unroll
    for (int cc = 0; cc < 2; ++cc){
      int c = tid + cc*256;
      const float* cr = cb + (size_t)c * SYM;
      float d = 0.f;
      for (int j = 0; j < SYM; ++j) d += raw[j] * cr[j];
      float s = cnorm[c] - 2.f * d;
      if (s < bv){ bv = s; bi = c; }
    }
    rv[tid] = bv; ri[tid] = bi;
    __syncthreads();
    for (int off = 128; off; off >>= 1){
      if (tid < off){
        if (rv[tid+off] < rv[tid] || (rv[tid+off] == rv[tid] && ri[tid+off] < ri[tid])){
          rv[tid] = rv[tid+off]; ri[tid] = ri[tid+off];
        }
      }
      __syncthreads();
    }
    int idx = ri[0];
    if (tid == 0) out_idx[m] = (float)idx;
    float cvv = cb[(size_t)idx * SYM + tid];
    out_q[(size_t)m * SYM + tid] = cvv;
    q_h[(size_t)m * SYM + tid] = f2bf(cvv);
    __syncthreads();
  }
}

} // namespace

extern "C" void kernel_launch(void* const* d_in, const int* in_sizes, int n_in,
                              void* d_out, int out_size, void* d_ws, size_t ws_size,
                              hipStream_t stream){
  const float* token_state = (const float*)d_in[0];
  const float* bus_symbols = (const float*)d_in[1];
  const float* bus_outputs = (const float*)d_in[3];
  const float* Wq    = (const float*)d_in[5];
  const float* Wread = (const float*)d_in[7];
  const float* bread = (const float*)d_in[8];
  const float* Wsym  = (const float*)d_in[9];
  const float* bsym  = (const float*)d_in[10];
  const float* Wc1   = (const float*)d_in[11];
  const float* bc1   = (const float*)d_in[12];
  const float* Wc2   = (const float*)d_in[13];
  const float* bc2   = (const float*)d_in[14];
  const float* codebook = (const float*)d_in[15];

  float* out_node = (float*)d_out;                       // [NTOK*LAT]
  float* out_quant= out_node + (size_t)NTOK * LAT;       // [NTOK*SYM]
  float* out_idx  = out_quant + (size_t)NTOK * SYM;      // [NTOK]
  float* out_mask = out_idx + NTOK;                      // [T]

  // ---- workspace layout (256B aligned) ----
  char* W = (char*)d_ws; size_t off = 0;
  auto alloc = [&](size_t bytes)->char*{ char* p = W + off; off = (off + bytes + 255) & ~(size_t)255; return p; };
  int*   top     = (int*)alloc(NTOK*4);
  int*   counts  = (int*)alloc(64);
  int*   rcount  = (int*)alloc(64);
  int*   rlist   = (int*)alloc(NTOK*4);
  float* cbT     = (float*)alloc((size_t)SYM*NC*4);
  float* cnorm   = (float*)alloc(NC*4);
  float* svec    = (float*)alloc(NC*4);
  float* rb      = (float*)alloc(SYM*4);
  float* Wfuse   = (float*)alloc((size_t)LAT*NC*4);
  float* Wcomb   = (float*)alloc((size_t)2*LAT*SYM*4);
  unsigned short* WreadT = (unsigned short*)alloc((size_t)LAT*2*LAT*2);
  unsigned short* Wc1T   = (unsigned short*)alloc((size_t)LAT*(LAT+SYM)*2);
  unsigned short* Wc2T   = (unsigned short*)alloc((size_t)LAT*LAT*2);
  unsigned short* WfuseT = (unsigned short*)alloc((size_t)NC*LAT*2);
  unsigned short* z_h    = (unsigned short*)alloc((size_t)NTOK*LAT*2);
  unsigned short* q_h    = (unsigned short*)alloc((size_t)NTOK*SYM*2);
  unsigned short* h_h    = (unsigned short*)alloc((size_t)NTOK*LAT*2);
  char* az_region        = alloc((size_t)NTOK*2*LAT*2);     // A_z bf16 (32MB)
  unsigned short* A_z    = (unsigned short*)az_region;
  float* scores          = (float*)az_region;               // overlay: A_z dead before scores written

  hipMemsetAsync(counts, 0, T_*sizeof(int), stream);
  hipMemsetAsync(rcount, 0, sizeof(int), stream);

  route_k<<<NTOK/4, 256, 0, stream>>>(bus_symbols, Wq, top, counts);
  mask_k<<<1, 64, 0, stream>>>(counts, out_mask);
  cbt_k<<<(NC*SYM)/256, 256, 0, stream>>>(codebook, cbT);
  cnorm_k<<<NC/4, 256, 0, stream>>>(codebook, bsym, cnorm, svec);
  rbias_k<<<1, SYM, 0, stream>>>(bread, Wsym, bsym, rb);

  // Wfuse = Wsym @ cbT  [LAT x NC] f32, then transpose->bf16 [NC x LAT]
  gemm_f32<64,64,8,4,4><<<dim3(LAT/64, NC/64), 256, 0, stream>>>(Wsym, cbT, Wfuse, LAT, NC, SYM);
  t32_k<<<dim3(NC/32, LAT/32), 256, 0, stream>>>(Wfuse, WfuseT, LAT, NC);
  // Wcomb = Wread @ Wsym  [2LAT x SYM] f32 (repair path)
  gemm_f32<64,64,8,4,4><<<dim3(2*LAT/64, SYM/64), 256, 0, stream>>>(Wread, Wsym, Wcomb, 2*LAT, SYM, LAT);
  // weight transposes -> bf16 BT layout
  t32_k<<<dim3(LAT/32, 2*LAT/32), 256, 0, stream>>>(Wread, WreadT, 2*LAT, LAT);
  t32_k<<<dim3(LAT/32, (LAT+SYM)/32), 256, 0, stream>>>(Wc1, Wc1T, LAT+SYM, LAT);
  t32_k<<<dim3(LAT/32, LAT/32), 256, 0, stream>>>(Wc2, Wc2T, LAT, LAT);

  pack_az<<<(NTOK*512)/256, 256, 0, stream>>>(token_state, bus_outputs, top, A_z);

  // z_h = bf16(A_z @ WreadT^T + bread)   [NTOK x LAT]
  mgemm<A_PLAIN, EP_ZH><<<dim3(LAT/128, NTOK/128), 256, 0, stream>>>(
      A_z, nullptr, WreadT, bread, nullptr, z_h, nullptr, LAT, 2*LAT, 0);
  // scores = svec - 2 * z_h @ WfuseT^T   [NTOK x NC] f32 (overlay on A_z)
  mgemm<A_PLAIN, EP_VQ><<<dim3(NC/128, NTOK/128), 256, 0, stream>>>(
      z_h, nullptr, WfuseT, svec, nullptr, nullptr, scores, NC, LAT, 0);

  vq_k<<<NTOK/4, 256, 0, stream>>>(scores, codebook, out_quant, out_idx, q_h, rcount, rlist);
  repair_k<<<120, 256, 0, stream>>>(rcount, rlist, top, token_state, bus_outputs,
                                    Wcomb, rb, codebook, cnorm, out_quant, out_idx, q_h);

  // h_h = bf16(relu([z_h | q_h] @ Wc1T^T + bc1))
  mgemm<A_CAT, EP_RELU><<<dim3(LAT/128, NTOK/128), 256, 0, stream>>>(
      z_h, q_h, Wc1T, bc1, nullptr, h_h, nullptr, LAT, LAT+SYM, LAT);
  // out_node = h_h @ Wc2T^T + bc2 + token_state   (f32)
  mgemm<A_PLAIN, EP_OUT><<<dim3(LAT/128, NTOK/128), 256, 0, stream>>>(
      h_h, nullptr, Wc2T, bc2, token_state, nullptr, out_node, LAT, LAT, 0);
}